// Round 14
// baseline (124.008 us; speedup 1.0000x reference)
//
#include <hip/hip_runtime.h>
#include <hip/hip_bf16.h>

#define BATCH 16
#define SEQ   2048
#define DIM   128
#define QBLK  64       // q rows per block (4 waves x 16)
#define KVB   32       // kv per tile
#define NT    (SEQ / KVB)   // 64 tiles
#define L2E   1.4426950408889634f
#define THR   8.0f
#define MSENT -100

typedef __attribute__((ext_vector_type(8))) short bf16x8;
typedef __attribute__((ext_vector_type(4))) float f32x4;
typedef __attribute__((ext_vector_type(4))) int   i32x4;
typedef __attribute__((ext_vector_type(4))) unsigned u32x4;

__device__ __forceinline__ unsigned short f2bf(float f) {
  union { float f; unsigned u; } v; v.f = f;
  return (unsigned short)((v.u + 0x7FFFu + ((v.u >> 16) & 1u)) >> 16);  // RTNE
}
__device__ __forceinline__ unsigned packbf(float a, float b) {
  return ((unsigned)f2bf(b) << 16) | (unsigned)f2bf(a);
}

// ---------------- Pass 1a: K f32 -> bf16 (same layout) ----------------
__global__ __launch_bounds__(256) void cvt_k(const float* __restrict__ K,
                                             short* __restrict__ Kb) {
  const size_t i = ((size_t)blockIdx.x * 256 + threadIdx.x) * 8;
  f32x4 a = __builtin_nontemporal_load((const f32x4*)(K + i));
  f32x4 b = __builtin_nontemporal_load((const f32x4*)(K + i + 4));
  u32x4 o = { packbf(a[0], a[1]), packbf(a[2], a[3]),
              packbf(b[0], b[1]), packbf(b[2], b[3]) };
  *(u32x4*)(Kb + i) = o;
}

// ---------------- Pass 1b: V f32 [b][s][d] -> bf16 Vt [b][d][s] ----------------
__global__ __launch_bounds__(256) void cvt_vt(const float* __restrict__ V,
                                              short* __restrict__ Vt) {
  __shared__ unsigned t32[64][65];
  const int tid = threadIdx.x;
  const int b  = blockIdx.x >> 5;
  const int s0 = (blockIdx.x & 31) * 64;
  #pragma unroll
  for (int it = 0; it < 8; ++it) {
    const int idx = tid + it * 256;
    const int r = idx >> 5, c4 = idx & 31;
    f32x4 x = __builtin_nontemporal_load(
        (const f32x4*)(V + ((size_t)b * SEQ + s0 + r) * DIM + c4 * 4));
    t32[r][c4 * 2]     = packbf(x[0], x[1]);
    t32[r][c4 * 2 + 1] = packbf(x[2], x[3]);
  }
  __syncthreads();
  const int d = tid >> 1, sh = tid & 1;
  unsigned short outv[32];
  #pragma unroll
  for (int j = 0; j < 32; ++j) {
    const unsigned u = t32[sh * 32 + j][d >> 1];
    outv[j] = (d & 1) ? (unsigned short)(u >> 16) : (unsigned short)(u & 0xffff);
  }
  short* op = Vt + ((size_t)b * DIM + d) * SEQ + s0 + sh * 32;
  #pragma unroll
  for (int q = 0; q < 4; ++q) {
    bf16x8 y;
    #pragma unroll
    for (int j = 0; j < 8; ++j) y[j] = (short)outv[q * 8 + j];
    *(bf16x8*)(op + q * 8) = y;
  }
}

// ---------------- async 16B global->LDS ----------------
__device__ __forceinline__ void gload16(const void* g, void* l) {
  __builtin_amdgcn_global_load_lds(
      (const __attribute__((address_space(1))) unsigned*)g,
      (__attribute__((address_space(3))) unsigned*)l, 16, 0, 0);
}

// K tile [32 rows x 256B]; linear LDS dest, pre-swizzled source (rule #21).
__device__ __forceinline__ void stage_k32(const char* __restrict__ Kb2,
                                          int k0, int w, int l, void* kbuf) {
  #pragma unroll
  for (int it = 0; it < 2; ++it) {
    const int ch = w * 2 + it;                // 1KB chunk 0..7
    const int r  = ch * 4 + (l >> 4);         // K row 0..31
    const int sg = (l & 15) ^ (r & 15);
    gload16(Kb2 + (size_t)(k0 + r) * 256 + sg * 16, (char*)kbuf + ch * 1024);
  }
}
// V tile [128 d-rows x 64B]; same both-sides swizzle scheme (R8-proven).
__device__ __forceinline__ void stage_v32(const char* __restrict__ Vtb2,
                                          int k0, int w, int l, void* vbuf) {
  #pragma unroll
  for (int it = 0; it < 2; ++it) {
    const int ch = w * 2 + it;
    const int d  = ch * 16 + (l >> 2);        // V row (d) 0..127
    const int sp = (l & 3) ^ ((l >> 3) & 3);  // content(d,s) = s ^ ((d>>1)&3)
    gload16(Vtb2 + (size_t)d * (SEQ * 2) + (size_t)k0 * 2 + sp * 16,
            (char*)vbuf + ch * 1024);
  }
}

// One pipelined tile. Invariant at entry of tile T:
//   kA=k[T%3], kB=k[(T+1)%3], kC=k[(T+2)%3]; vA=v[T%3], vB=v[(T+1)%3], vC=v[(T+2)%3]
// Stage K(T+3)->kA (read finished during T-1), V(T+2)->vC; QK(T+1) reads kB;
// PV(T) reads vA.  BARMODE 0: counted vmcnt(6)+s_barrier (this tile's 6 VMEM
// ride across); BARMODE 1: full __syncthreads (tail).  Rotate pointers at end.
#define TILE_BODY(T, SA, SB, MA, MB, BARMODE)                                  \
  {                                                                            \
    if ((T) + 3 < NT) stage_k32(Kb2, ((T) + 3) * KVB, w, l, kA);               \
    if ((T) + 2 < NT) stage_v32(Vtb2, ((T) + 2) * KVB, w, l, vC);              \
    if ((T) + 1 < NT) {                                                        \
      MB[0] = __builtin_nontemporal_load(                                      \
          (const i32x4*)(Mr + ((T) + 1) * KVB + 4 * g));                       \
      MB[1] = __builtin_nontemporal_load(                                      \
          (const i32x4*)(Mr + ((T) + 1) * KVB + 16 + 4 * g));                  \
    }                                                                          \
    __builtin_amdgcn_sched_barrier(0);                                         \
    /* mask apply + online softmax (tile T), lane-local q = lr */              \
    _Pragma("unroll") for (int sub = 0; sub < 2; ++sub)                        \
        _Pragma("unroll") for (int i = 0; i < 4; ++i)                          \
            if (MA[sub][i] == MSENT) SA[sub][i] = -1e30f;                      \
    {                                                                          \
      float tm = fmaxf(fmaxf(SA[0][0], SA[0][1]), fmaxf(SA[0][2], SA[0][3])); \
      tm = fmaxf(tm, fmaxf(fmaxf(SA[1][0], SA[1][1]),                          \
                           fmaxf(SA[1][2], SA[1][3])));                        \
      tm = fmaxf(tm, __shfl_xor(tm, 16));                                      \
      tm = fmaxf(tm, __shfl_xor(tm, 32));                                      \
      if (__any(tm > mrow + THR)) {                                            \
        const float mnew = fmaxf(mrow, tm);                                    \
        const float al = __builtin_amdgcn_exp2f((mrow - mnew) * L2E);          \
        mrow = mnew; lsum *= al;                                               \
        float av[4];                                                           \
        _Pragma("unroll") for (int i = 0; i < 4; ++i)                          \
            av[i] = __shfl(al, 4 * g + i);                                     \
        _Pragma("unroll") for (int t8 = 0; t8 < 8; ++t8)                       \
            _Pragma("unroll") for (int i = 0; i < 4; ++i)                      \
                acc[t8][i] *= av[i];                                           \
      }                                                                        \
    }                                                                          \
    /* QK(T+1) from kB — MFMA pipe, overlaps P VALU below */                   \
    if ((T) + 1 < NT) {                                                        \
      SB[0] = (f32x4){0.f, 0.f, 0.f, 0.f};                                     \
      SB[1] = (f32x4){0.f, 0.f, 0.f, 0.f};                                     \
      __builtin_amdgcn_s_setprio(1);                                           \
      _Pragma("unroll") for (int kk = 0; kk < 4; ++kk) {                       \
        const int cb = (64 * kk + 16 * g) ^ (lr << 4);                         \
        bf16x8 kb0 = *(const bf16x8*)(kB + lr * 256 + cb);                     \
        bf16x8 kb1 = *(const bf16x8*)(kB + (16 + lr) * 256 + cb);              \
        SB[0] = __builtin_amdgcn_mfma_f32_16x16x32_bf16(kb0, qa[kk], SB[0],    \
                                                        0, 0, 0);              \
        SB[1] = __builtin_amdgcn_mfma_f32_16x16x32_bf16(kb1, qa[kk], SB[1],    \
                                                        0, 0, 0);              \
      }                                                                        \
      __builtin_amdgcn_s_setprio(0);                                           \
    }                                                                          \
    /* P(T): exp2 + packbf + in-register redistribute (R8-proven), then PV */  \
    {                                                                          \
      unsigned pk[2][2];                                                       \
      _Pragma("unroll") for (int sub = 0; sub < 2; ++sub) {                    \
        const float p0 = __builtin_amdgcn_exp2f((SA[sub][0] - mrow) * L2E);    \
        const float p1 = __builtin_amdgcn_exp2f((SA[sub][1] - mrow) * L2E);    \
        const float p2 = __builtin_amdgcn_exp2f((SA[sub][2] - mrow) * L2E);    \
        const float p3 = __builtin_amdgcn_exp2f((SA[sub][3] - mrow) * L2E);    \
        lsum += (p0 + p1) + (p2 + p3);                                         \
        pk[sub][0] = packbf(p0, p1);                                           \
        pk[sub][1] = packbf(p2, p3);                                           \
      }                                                                        \
      const unsigned s00 = (unsigned)__shfl((int)pk[0][0], laneA);             \
      const unsigned s01 = (unsigned)__shfl((int)pk[0][1], laneA);             \
      const unsigned s02 = (unsigned)__shfl((int)pk[0][0], laneB);             \
      const unsigned s03 = (unsigned)__shfl((int)pk[0][1], laneB);             \
      const unsigned s10 = (unsigned)__shfl((int)pk[1][0], laneA);             \
      const unsigned s11 = (unsigned)__shfl((int)pk[1][1], laneA);             \
      const unsigned s12 = (unsigned)__shfl((int)pk[1][0], laneB);             \
      const unsigned s13 = (unsigned)__shfl((int)pk[1][1], laneB);             \
      const bool hi = (g >= 2);                                                \
      union { unsigned u[4]; bf16x8 v; } pa;                                   \
      pa.u[0] = hi ? s10 : s00;                                                \
      pa.u[1] = hi ? s11 : s01;                                                \
      pa.u[2] = hi ? s12 : s02;                                                \
      pa.u[3] = hi ? s13 : s03;                                                \
      const int Sv = ((g ^ ((lr >> 1) & 3)) << 4);                             \
      __builtin_amdgcn_s_setprio(1);                                           \
      _Pragma("unroll") for (int t8 = 0; t8 < 8; ++t8) {                       \
        bf16x8 vb = *(const bf16x8*)(vA + (16 * t8 + lr) * 64 + Sv);           \
        acc[t8] = __builtin_amdgcn_mfma_f32_16x16x32_bf16(pa.v, vb, acc[t8],   \
                                                          0, 0, 0);            \
      }                                                                        \
      __builtin_amdgcn_s_setprio(0);                                           \
    }                                                                          \
    if ((T) + 1 < NT) {                                                        \
      if (BARMODE) {                                                           \
        __syncthreads();                                                       \
      } else {                                                                 \
        asm volatile("s_waitcnt vmcnt(6)" ::: "memory");                       \
        __builtin_amdgcn_s_barrier();                                          \
        __builtin_amdgcn_sched_barrier(0);                                     \
      }                                                                        \
    }                                                                          \
    { char* t_ = kA; kA = kB; kB = kC; kC = t_; }                              \
    { char* t_ = vA; vA = vB; vB = vC; vC = t_; }                              \
  }

// ---------------- Pass 2: deep-pipelined flash attention ----------------
__global__ __launch_bounds__(256, 2) void attn_fwd(
    const short* __restrict__ Kbf, const short* __restrict__ Vt,
    const float* __restrict__ Qg, const int* __restrict__ Mg,
    float* __restrict__ Og) {
  __shared__ short lds_k[3][KVB * DIM];   // 3 x 8KB
  __shared__ short lds_v[3][DIM * KVB];   // 3 x 8KB  (48KB total)

  const int tid = threadIdx.x;
  const int w = tid >> 6, l = tid & 63, g = l >> 4, lr = l & 15;

  const int blk = blockIdx.x;
  const int swz = (blk & 7) * 64 + (blk >> 3);   // XCD-chunked (512 % 8 == 0)
  const int b   = swz >> 5;
  const int q0  = (swz & 31) * QBLK;

  const float scale = 0.08838834764831845f;  // 1/sqrt(128)

  const char* Kb2  = (const char*)(Kbf + (size_t)b * SEQ * DIM);
  const char* Vtb2 = (const char*)(Vt  + (size_t)b * DIM * SEQ);
  const int*  Mr   = Mg + (size_t)b * SEQ * SEQ + (size_t)(q0 + w * 16 + lr) * SEQ;

  char *kA = (char*)lds_k[0], *kB = (char*)lds_k[1], *kC = (char*)lds_k[2];
  char *vA = (char*)lds_v[0], *vB = (char*)lds_v[1], *vC = (char*)lds_v[2];

  // ---- prologue staging: K(0,1,2), V(0,1); mask(0)
  stage_k32(Kb2, 0,       w, l, kA);
  stage_k32(Kb2, KVB,     w, l, kB);
  stage_k32(Kb2, 2 * KVB, w, l, kC);
  stage_v32(Vtb2, 0,      w, l, vA);
  stage_v32(Vtb2, KVB,    w, l, vB);
  __builtin_amdgcn_sched_barrier(0);
  i32x4 mA[2], mB[2];
  mA[0] = __builtin_nontemporal_load((const i32x4*)(Mr + 4 * g));
  mA[1] = __builtin_nontemporal_load((const i32x4*)(Mr + 16 + 4 * g));

  // ---- Q fragments (q = lr; B operand of swapped QK), pre-scaled
  bf16x8 qa[4];
  {
    const float* qbase = Qg + ((size_t)b * SEQ + (size_t)(q0 + w * 16 + lr)) * DIM + g * 8;
    #pragma unroll
    for (int kk = 0; kk < 4; ++kk) {
      f32x4 x0 = *(const f32x4*)(qbase + kk * 32);
      f32x4 x1 = *(const f32x4*)(qbase + kk * 32 + 4);
      bf16x8 f;
      #pragma unroll
      for (int j = 0; j < 4; ++j) {
        f[j]     = (short)f2bf(x0[j] * scale);
        f[j + 4] = (short)f2bf(x1[j] * scale);
      }
      qa[kk] = f;
    }
  }

  f32x4 acc[8];
  #pragma unroll
  for (int t = 0; t < 8; ++t) acc[t] = (f32x4){0.f, 0.f, 0.f, 0.f};
  float mrow = -1e30f, lsum = 0.f;

  const int laneA = ((g & 1) << 5) + lr;        // R8-proven redistribution lanes
  const int laneB = laneA + 16;

  __syncthreads();   // full drain: all prologue staging + Q + mask landed

  // ---- prologue QK(0) from kA -> sA
  f32x4 sA[2], sB[2];
  sA[0] = (f32x4){0.f, 0.f, 0.f, 0.f};
  sA[1] = (f32x4){0.f, 0.f, 0.f, 0.f};
  #pragma unroll
  for (int kk = 0; kk < 4; ++kk) {
    const int cb = (64 * kk + 16 * g) ^ (lr << 4);
    bf16x8 kb0 = *(const bf16x8*)(kA + lr * 256 + cb);
    bf16x8 kb1 = *(const bf16x8*)(kA + (16 + lr) * 256 + cb);
    sA[0] = __builtin_amdgcn_mfma_f32_16x16x32_bf16(kb0, qa[kk], sA[0], 0, 0, 0);
    sA[1] = __builtin_amdgcn_mfma_f32_16x16x32_bf16(kb1, qa[kk], sA[1], 0, 0, 0);
  }
  __syncthreads();   // all waves done reading k[0] before tile 0 stages into it

  // ---- main loop: tiles 0..59 counted-vmcnt; tail 60..63 full drain
  for (int t = 0; t < 60; t += 2) {
    TILE_BODY(t,     sA, sB, mA, mB, 0);
    TILE_BODY(t + 1, sB, sA, mB, mA, 0);
  }
  TILE_BODY(60, sA, sB, mA, mB, 1);
  TILE_BODY(61, sB, sA, mB, mA, 1);
  TILE_BODY(62, sA, sB, mA, mB, 1);
  TILE_BODY(63, sB, sA, mB, mA, 1);

  // ---- finalize: full row sum, normalize, store
  lsum += __shfl_xor(lsum, 16);
  lsum += __shfl_xor(lsum, 32);
  const float rden = 1.f / lsum;   // valid for q = lr
  float rdv[4];
  #pragma unroll
  for (int i = 0; i < 4; ++i) rdv[i] = __shfl(rden, 4 * g + i);
  float* ob = Og + ((size_t)b * SEQ + (size_t)(q0 + w * 16)) * DIM;
  #pragma unroll
  for (int t8 = 0; t8 < 8; ++t8)
    #pragma unroll
    for (int i = 0; i < 4; ++i)
      ob[(4 * g + i) * DIM + 16 * t8 + lr] = acc[t8][i] * rdv[i];
}

extern "C" void kernel_launch(void* const* d_in, const int* in_sizes, int n_in,
                              void* d_out, int out_size, void* d_ws, size_t ws_size,
                              hipStream_t stream) {
  (void)in_sizes; (void)n_in; (void)out_size; (void)ws_size;
  const float* Vg = (const float*)d_in[0];
  const float* Kg = (const float*)d_in[1];
  const float* Qg = (const float*)d_in[2];
  const int*   Mg = (const int*)d_in[3];
  float* Og = (float*)d_out;

  short* Kbf = (short*)d_ws;                       // 8 MB
  short* Vt  = Kbf + (size_t)BATCH * SEQ * DIM;    // 8 MB
  cvt_k<<<dim3(BATCH * SEQ * DIM / (8 * 256)), 256, 0, stream>>>(Kg, Kbf);
  cvt_vt<<<dim3(BATCH * (SEQ / 64)), 256, 0, stream>>>(Vg, Vt);
  attn_fwd<<<dim3(BATCH * (SEQ / QBLK)), 256, 0, stream>>>(Kbf, Vt, Qg, Mg, Og);
}